// Round 1
// baseline (1812.509 us; speedup 1.0000x reference)
//
#include <hip/hip_runtime.h>

#define B_   64
#define T_   1024
#define C_   256
#define BM   32
#define BN   32
#define NEGF (-4294967295.0f)   // float(-2**32+1) rounds to -2^32, same as reference fp32 cast
#define LN_EPS 1e-9f

// ---------------------------------------------------------------------------
// ws layout (bytes):
//   [0      , 65536 )  float accum[B][C]   (sum over t of LN'd rows)
//   [65536  , 131072)  float colsum[B][C]  (per-batch column sums of x)
//   [131072 , 131136)  int   flag (mask dtype: 1 = byte-packed bool, 0 = int32)
//   [131136 , 196672)  u8    mask8[B*T]    (normalized key mask)
// ---------------------------------------------------------------------------

// XOR-swizzled LDS addressing: row r, logical float4-chunk k (0..63)
// -> physical float index. Conflict-free for both row-wise (QK^T) and
// column-strided (PV) wave access patterns without padding (fits 64 KB).
__device__ __forceinline__ int sw(int r, int chunk) {
  return (r << 8) + ((chunk ^ (r & 7)) << 2);
}

__global__ void detect_kernel(const unsigned int* __restrict__ mw,
                              int* __restrict__ flag) {
  int idx = blockIdx.x * 256 + threadIdx.x;   // 16384 words = 64 KB, safe for u8 or i32 buffer
  if (mw[idx] > 1u) atomicOr(flag, 1);        // byte-packed bools produce words > 1
}

__global__ void normalize_kernel(const unsigned int* __restrict__ mw,
                                 const int* __restrict__ flag,
                                 unsigned char* __restrict__ mask8) {
  int idx = blockIdx.x * 256 + threadIdx.x;   // B*T = 65536
  int f = *flag;
  // single load; address depends on detected dtype (no speculative OOB reads)
  unsigned int w = mw[f ? (idx >> 2) : idx];
  unsigned int v = f ? ((w >> ((idx & 3) * 8)) & 0xffu) : w;
  mask8[idx] = (unsigned char)(v != 0u);
}

__global__ void colsum_kernel(const float* __restrict__ x,
                              float* __restrict__ colsum) {
  int b = blockIdx.x, chunk = blockIdx.y, c = threadIdx.x;
  const float* xp = x + ((size_t)b * T_ + (size_t)chunk * 128) * C_ + c;
  float s = 0.f;
  for (int t = 0; t < 128; ++t) s += xp[(size_t)t * C_];
  atomicAdd(&colsum[b * C_ + c], s);
}

// Fused causal flash attention + LayerNorm + block-partial time-mean.
// Block: 256 threads = one (batch b, 32-query tile). Thread (i = tid>>3,
// cg = tid&7) owns row i, columns {32*cc + 4*cg + e}, and scores j = cg+8r.
__global__ __launch_bounds__(256, 2) void flash_kernel(
    const float* __restrict__ x,
    const unsigned char* __restrict__ mask,
    const float* __restrict__ gamma,
    const float* __restrict__ beta,
    const float* __restrict__ colsum,
    float* __restrict__ accum)
{
  __shared__ float Qs[BM * C_];   // 32 KB, swizzled
  __shared__ float Ks[BN * C_];   // 32 KB, swizzled (K and V are the same tensor)

  const int tid = threadIdx.x;
  const int b   = blockIdx.x >> 5;     // T_/BM = 32 query tiles
  const int qt  = blockIdx.x & 31;
  const int i   = tid >> 3;            // row within tile, 0..31
  const int cg  = tid & 7;             // col/score group, 0..7

  const float* xb = x + (size_t)b * (T_ * C_);
  const unsigned char* mb = mask + b * T_;

  // load Q tile (coalesced global float4 -> swizzled LDS)
  for (int v = tid; v < BM * 64; v += 256) {
    int r = v >> 6, ck = v & 63;
    *(float4*)&Qs[sw(r, ck)] =
        *(const float4*)(xb + (size_t)(qt * BM + r) * C_ + (ck << 2));
  }

  float O[32];
#pragma unroll
  for (int e = 0; e < 32; ++e) O[e] = 0.f;
  float m = NEGF, l = 0.f;
  const int trow = qt * BM + i;

  for (int kt = 0; kt <= qt; ++kt) {
    __syncthreads();                      // prior-iter Ks reads done
    for (int v = tid; v < BN * 64; v += 256) {
      int r = v >> 6, ck = v & 63;
      *(float4*)&Ks[sw(r, ck)] =
          *(const float4*)(xb + (size_t)(kt * BN + r) * C_ + (ck << 2));
    }
    __syncthreads();

    // ---- scores: 4 dots of length 256 per thread, conflict-free b128 reads
    float s0 = 0.f, s1 = 0.f, s2 = 0.f, s3 = 0.f;
#pragma unroll 8
    for (int kk = 0; kk < 64; ++kk) {
      float4 q  = *(float4*)&Qs[sw(i, kk)];          // broadcast across cg lanes
      float4 a0 = *(float4*)&Ks[sw(cg,      kk)];    // banks spread by cg
      float4 a1 = *(float4*)&Ks[sw(cg + 8,  kk)];
      float4 a2 = *(float4*)&Ks[sw(cg + 16, kk)];
      float4 a3 = *(float4*)&Ks[sw(cg + 24, kk)];
      s0 += q.x*a0.x + q.y*a0.y + q.z*a0.z + q.w*a0.w;
      s1 += q.x*a1.x + q.y*a1.y + q.z*a1.z + q.w*a1.w;
      s2 += q.x*a2.x + q.y*a2.y + q.z*a2.z + q.w*a2.w;
      s3 += q.x*a3.x + q.y*a3.y + q.z*a3.z + q.w*a3.w;
    }

    const int sb = kt * BN;
    float sc0 = (sb + cg      <= trow && mb[sb + cg])      ? s0 * 0.0625f : NEGF;
    float sc1 = (sb + cg + 8  <= trow && mb[sb + cg + 8])  ? s1 * 0.0625f : NEGF;
    float sc2 = (sb + cg + 16 <= trow && mb[sb + cg + 16]) ? s2 * 0.0625f : NEGF;
    float sc3 = (sb + cg + 24 <= trow && mb[sb + cg + 24]) ? s3 * 0.0625f : NEGF;

    // ---- online softmax (exact NEG_INF semantics: all-masked rows stay at m=NEGF)
    float mt = fmaxf(fmaxf(sc0, sc1), fmaxf(sc2, sc3));
    mt = fmaxf(mt, __shfl_xor(mt, 1, 64));
    mt = fmaxf(mt, __shfl_xor(mt, 2, 64));
    mt = fmaxf(mt, __shfl_xor(mt, 4, 64));
    float mnew  = fmaxf(m, mt);
    float alpha = __expf(m - mnew);       // NEGF-NEGF=0 -> 1 ; NEGF-real -> 0 (wipes bogus uniform)
    float p0 = __expf(sc0 - mnew);
    float p1 = __expf(sc1 - mnew);
    float p2 = __expf(sc2 - mnew);
    float p3 = __expf(sc3 - mnew);
    float ps = p0 + p1 + p2 + p3;
    ps += __shfl_xor(ps, 1, 64);
    ps += __shfl_xor(ps, 2, 64);
    ps += __shfl_xor(ps, 4, 64);
    l = l * alpha + ps;
    m = mnew;

#pragma unroll
    for (int e = 0; e < 32; ++e) O[e] *= alpha;

    // ---- PV: O[i][c] += sum_j P[i][j] * K[j][c]; P broadcast via shfl in 8-lane row group
    const int lbase = tid & 56;           // base lane of this row's group (mod-64 safe)
    float parr[4] = {p0, p1, p2, p3};
#pragma unroll
    for (int jr = 0; jr < 4; ++jr) {
      float pbase = parr[jr];
#pragma unroll 2
      for (int jj = 0; jj < 8; ++jj) {
        float pj = __shfl(pbase, lbase + jj, 64);
        const int j = jr * 8 + jj;
#pragma unroll
        for (int cc = 0; cc < 8; ++cc) {
          float4 kv = *(float4*)&Ks[sw(j, (cc << 3) + cg)];
          O[(cc << 2) + 0] += pj * kv.x;
          O[(cc << 2) + 1] += pj * kv.y;
          O[(cc << 2) + 2] += pj * kv.z;
          O[(cc << 2) + 3] += pj * kv.w;
        }
      }
    }
  }

  // ---- finalize attention row
  float o[32];
  if (m < -1.0e9f) {
    // fully-masked row: reference softmax is uniform 1/T over ALL keys
    const float* cs = colsum + b * C_;
#pragma unroll
    for (int cc = 0; cc < 8; ++cc) {
      float4 v = *(const float4*)(cs + (cc << 5) + (cg << 2));
      o[(cc << 2) + 0] = v.x * (1.0f / T_);
      o[(cc << 2) + 1] = v.y * (1.0f / T_);
      o[(cc << 2) + 2] = v.z * (1.0f / T_);
      o[(cc << 2) + 3] = v.w * (1.0f / T_);
    }
  } else {
    float inv = 1.0f / l;
#pragma unroll
    for (int e = 0; e < 32; ++e) o[e] = O[e] * inv;
  }

  // ---- LayerNorm over C (row split across 8 lanes)
  float sum = 0.f;
#pragma unroll
  for (int e = 0; e < 32; ++e) sum += o[e];
  sum += __shfl_xor(sum, 1, 64);
  sum += __shfl_xor(sum, 2, 64);
  sum += __shfl_xor(sum, 4, 64);
  const float mu = sum * (1.0f / C_);

  float sq = 0.f;
#pragma unroll
  for (int e = 0; e < 32; ++e) { float d = o[e] - mu; sq += d * d; }
  sq += __shfl_xor(sq, 1, 64);
  sq += __shfl_xor(sq, 2, 64);
  sq += __shfl_xor(sq, 4, 64);
  const float rstd = rsqrtf(sq * (1.0f / C_) + LN_EPS);

  __syncthreads();   // all waves past final score-stage Qs reads before reuse

  // write LN'd values into Qs (reused), then column-reduce over the 32 rows
#pragma unroll
  for (int cc = 0; cc < 8; ++cc) {
    const int c = (cc << 5) + (cg << 2);
    float4 g  = *(const float4*)(gamma + c);
    float4 bt = *(const float4*)(beta + c);
    float4 v;
    v.x = g.x * (o[(cc << 2) + 0] - mu) * rstd + bt.x;
    v.y = g.y * (o[(cc << 2) + 1] - mu) * rstd + bt.y;
    v.z = g.z * (o[(cc << 2) + 2] - mu) * rstd + bt.z;
    v.w = g.w * (o[(cc << 2) + 3] - mu) * rstd + bt.w;
    *(float4*)&Qs[sw(i, (cc << 3) + cg)] = v;
  }
  __syncthreads();

  float csum = 0.f;
  const int ck = tid >> 2, e4 = tid & 3;
#pragma unroll 8
  for (int r = 0; r < BM; ++r) csum += Qs[sw(r, ck) + e4];
  atomicAdd(&accum[b * C_ + tid], csum);
}

__global__ void finalize_kernel(const float* __restrict__ accum,
                                float* __restrict__ out) {
  int idx = blockIdx.x * 256 + threadIdx.x;   // B*C = 16384
  out[idx] = accum[idx] * (1.0f / T_);        // mean over time axis
}

extern "C" void kernel_launch(void* const* d_in, const int* in_sizes, int n_in,
                              void* d_out, int out_size, void* d_ws, size_t ws_size,
                              hipStream_t stream) {
  const float* x     = (const float*)d_in[0];
  const void*  km    = d_in[1];
  const float* gamma = (const float*)d_in[2];
  const float* beta  = (const float*)d_in[3];
  float* out = (float*)d_out;

  float* accum  = (float*)d_ws;                       // 16384 f
  float* colsum = accum + B_ * C_;                    // 16384 f
  int*   flag   = (int*)((char*)d_ws + 131072);
  unsigned char* mask8 = (unsigned char*)d_ws + 131136;

  // zero accum, colsum, flag
  hipMemsetAsync(d_ws, 0, 131136, stream);

  detect_kernel<<<64, 256, 0, stream>>>((const unsigned int*)km, flag);
  normalize_kernel<<<B_ * T_ / 256, 256, 0, stream>>>((const unsigned int*)km, flag, mask8);
  colsum_kernel<<<dim3(B_, 8), 256, 0, stream>>>(x, colsum);
  flash_kernel<<<B_ * (T_ / BM), 256, 0, stream>>>(x, mask8, gamma, beta, colsum, accum);
  finalize_kernel<<<B_ * C_ / 256, 256, 0, stream>>>(accum, out);
}

// Round 2
// 281.149 us; speedup vs baseline: 6.4468x; 6.4468x over previous
//
#include <hip/hip_runtime.h>

#define B_   64
#define T_   1024
#define C_   256
#define NEGF (-4294967295.0f)   // float(-2**32+1) == -2^32, matches reference fp32 cast
#define LN_EPS 1e-9f

typedef short  short8 __attribute__((ext_vector_type(8)));
typedef float  f32x4  __attribute__((ext_vector_type(4)));

union S8 { short8 v; unsigned int w[4]; };

// float -> bf16 (RNE), packed pair
__device__ __forceinline__ unsigned int pk2(float x, float y) {
  unsigned a = __float_as_uint(x); a = (a + 0x7fffu + ((a >> 16) & 1u)) >> 16;
  unsigned b = __float_as_uint(y); b = (b + 0x7fffu + ((b >> 16) & 1u)) >> 16;
  return a | (b << 16);
}

__device__ __forceinline__ float fc(const float4& v, int e) {
  return e == 0 ? v.x : e == 1 ? v.y : e == 2 ? v.z : v.w;
}

// K row-major [64][256] bf16, 32 chunks(16B)/row; swizzle keeps frag reads + writes balanced
__device__ __forceinline__ int swK(int row, int chunk) {
  return row * 256 + ((chunk ^ (row & 31)) << 3);
}
// V^T [256][64] bf16, 8 chunks/row
__device__ __forceinline__ int swV(int c, int chunk) {
  return c * 64 + (((chunk ^ (c >> 2) ^ (c << 1)) & 7) << 3);
}

__global__ void detect_kernel(const unsigned int* __restrict__ mw,
                              int* __restrict__ flag) {
  int idx = blockIdx.x * 256 + threadIdx.x;   // 16384 words, safe for u8 or i32 buffer
  if (mw[idx] > 1u) atomicOr(flag, 1);
}

__global__ void normalize_kernel(const unsigned int* __restrict__ mw,
                                 const int* __restrict__ flag,
                                 unsigned char* __restrict__ mask8) {
  int idx = blockIdx.x * 256 + threadIdx.x;   // B*T = 65536
  int f = *flag;
  unsigned int w = mw[f ? (idx >> 2) : idx];
  unsigned int v = f ? ((w >> ((idx & 3) * 8)) & 0xffu) : w;
  mask8[idx] = (unsigned char)(v != 0u);
}

__global__ void colsum_kernel(const float* __restrict__ x,
                              float* __restrict__ colsum) {
  int b = blockIdx.x, chunk = blockIdx.y, c = threadIdx.x;
  const float* xp = x + ((size_t)b * T_ + (size_t)chunk * 128) * C_ + c;
  float s = 0.f;
  for (int t = 0; t < 128; ++t) s += xp[(size_t)t * C_];
  atomicAdd(&colsum[b * C_ + c], s);
}

// MFMA flash attention + LN + partial time-mean.
// Block = 4 waves, handles batch b and the qt pair (p, 15-p): 17 K-tiles each.
// Wave w owns 16 query rows. S^T = K·Q^T via mfma 16x16x32 bf16.
__global__ __launch_bounds__(256, 2) void flash_mfma(
    const float* __restrict__ x,
    const unsigned char* __restrict__ mask,
    const float* __restrict__ gamma,
    const float* __restrict__ beta,
    const float* __restrict__ colsum,
    float* __restrict__ accum)
{
  __shared__ __align__(16) short Ks[64 * 256];   // 32 KB  K row-major bf16
  __shared__ __align__(16) short Vt[256 * 64];   // 32 KB  V^T bf16

  const int tid  = threadIdx.x;
  const int b    = blockIdx.x >> 3;
  const int pp   = blockIdx.x & 7;
  const int w    = tid >> 6;
  const int lane = tid & 63;
  const int quad = lane >> 4;
  const int r    = lane & 15;

  const float* xb = x + (size_t)b * (T_ * C_);
  const unsigned char* mb = mask + b * T_;
  const int cg = tid & 63, kg0 = tid >> 6;

  for (int half = 0; half < 2; ++half) {
    const int qt   = half ? (15 - pp) : pp;
    const int qrow = qt * 64 + w * 16 + r;

    // ---- Q fragments (B-operand of S^T): lane holds Q[qrow][ks*32+quad*8 .. +7]
    short8 qf[8];
#pragma unroll
    for (int ks = 0; ks < 8; ++ks) {
      const float* src = xb + (size_t)qrow * C_ + ks * 32 + quad * 8;
      float4 a  = *(const float4*)src;
      float4 c4 = *(const float4*)(src + 4);
      S8 s; s.w[0] = pk2(a.x, a.y);  s.w[1] = pk2(a.z, a.w);
            s.w[2] = pk2(c4.x, c4.y); s.w[3] = pk2(c4.z, c4.w);
      qf[ks] = s.v;
    }

    f32x4 Oa[16];
#pragma unroll
    for (int nt = 0; nt < 16; ++nt) Oa[nt] = (f32x4){0.f, 0.f, 0.f, 0.f};
    float m = NEGF, l = 0.f;

    for (int kt = 0; kt <= qt; ++kt) {
      __syncthreads();                              // prior-tile LDS reads done
      // ---- stage K tile (row-major bf16)
#pragma unroll
      for (int v = 0; v < 8; ++v) {
        int id = v * 256 + tid;
        int row = id >> 5, ck = id & 31;
        const float* src = xb + (size_t)(kt * 64 + row) * C_ + (ck << 3);
        float4 a  = *(const float4*)src;
        float4 c4 = *(const float4*)(src + 4);
        S8 s; s.w[0] = pk2(a.x, a.y);  s.w[1] = pk2(a.z, a.w);
              s.w[2] = pk2(c4.x, c4.y); s.w[3] = pk2(c4.z, c4.w);
        *(short8*)&Ks[swK(row, ck)] = s.v;
      }
      // ---- stage V^T tile (transpose in registers, b128 LDS writes)
#pragma unroll
      for (int u = 0; u < 2; ++u) {
        int kg = kg0 + u * 4;
        const float* src = xb + (size_t)(kt * 64 + kg * 8) * C_ + (cg << 2);
        float4 rv[8];
#pragma unroll
        for (int rr = 0; rr < 8; ++rr) rv[rr] = *(const float4*)(src + rr * C_);
#pragma unroll
        for (int e = 0; e < 4; ++e) {
          S8 s;
          s.w[0] = pk2(fc(rv[0], e), fc(rv[1], e));
          s.w[1] = pk2(fc(rv[2], e), fc(rv[3], e));
          s.w[2] = pk2(fc(rv[4], e), fc(rv[5], e));
          s.w[3] = pk2(fc(rv[6], e), fc(rv[7], e));
          *(short8*)&Vt[swV(cg * 4 + e, kg)] = s.v;
        }
      }
      __syncthreads();

      // ---- scores S^T = K · Q^T  (D[m=j][n=q], q = qrow at lane&15)
      float sc[16];
#pragma unroll
      for (int mt = 0; mt < 4; ++mt) {
        f32x4 acc = (f32x4){0.f, 0.f, 0.f, 0.f};
#pragma unroll
        for (int ks = 0; ks < 8; ++ks) {
          short8 af = *(short8*)&Ks[swK(mt * 16 + r, ks * 4 + quad)];
          acc = __builtin_amdgcn_mfma_f32_16x16x32_bf16(af, qf[ks], acc, 0, 0, 0);
        }
        const int jb = kt * 64 + mt * 16 + quad * 4;
#pragma unroll
        for (int reg = 0; reg < 4; ++reg) {
          int j = jb + reg;
          sc[mt * 4 + reg] = (j <= qrow && mb[j]) ? acc[reg] * 0.0625f : NEGF;
        }
      }

      // ---- online softmax (per q-row stats at lane&15, replicated via xor16/32)
      float mx = sc[0];
#pragma unroll
      for (int i = 1; i < 16; ++i) mx = fmaxf(mx, sc[i]);
      mx = fmaxf(mx, __shfl_xor(mx, 16, 64));
      mx = fmaxf(mx, __shfl_xor(mx, 32, 64));
      float mnew  = fmaxf(m, mx);
      float alpha = __expf(m - mnew);   // NEGF-NEGF=0 -> 1; NEGF-real -> 0 wipes garbage
      float p[16], ps = 0.f;
#pragma unroll
      for (int i = 0; i < 16; ++i) { p[i] = __expf(sc[i] - mnew); ps += p[i]; }
      ps += __shfl_xor(ps, 16, 64);
      ps += __shfl_xor(ps, 32, 64);
      l = l * alpha + ps;
      m = mnew;

      float ar[4];
#pragma unroll
      for (int reg = 0; reg < 4; ++reg) ar[reg] = __shfl(alpha, quad * 4 + reg, 64);
#pragma unroll
      for (int nt = 0; nt < 16; ++nt) {
        Oa[nt][0] *= ar[0]; Oa[nt][1] *= ar[1];
        Oa[nt][2] *= ar[2]; Oa[nt][3] *= ar[3];
      }

      // ---- P (C-layout) -> PV A-operand frags via shuffles, bf16-packed
      S8 pf[2];
#pragma unroll
      for (int ks = 0; ks < 2; ++ks) {
        unsigned a01 = pk2(p[ks * 8 + 0], p[ks * 8 + 1]);
        unsigned a23 = pk2(p[ks * 8 + 2], p[ks * 8 + 3]);
        unsigned b01 = pk2(p[ks * 8 + 4], p[ks * 8 + 5]);
        unsigned b23 = pk2(p[ks * 8 + 6], p[ks * 8 + 7]);
        int s0 = ((quad & 1) << 5) + r;   // src quad (quad&1)*2, same n-col
        int s1 = s0 + 16;
        unsigned va01 = __shfl((int)a01, s0, 64), vb01 = __shfl((int)b01, s0, 64);
        unsigned va23 = __shfl((int)a23, s0, 64), vb23 = __shfl((int)b23, s0, 64);
        unsigned wa01 = __shfl((int)a01, s1, 64), wb01 = __shfl((int)b01, s1, 64);
        unsigned wa23 = __shfl((int)a23, s1, 64), wb23 = __shfl((int)b23, s1, 64);
        bool hi = (quad & 2) != 0;
        pf[ks].w[0] = hi ? vb01 : va01;   // jj 0,1
        pf[ks].w[1] = hi ? vb23 : va23;   // jj 2,3
        pf[ks].w[2] = hi ? wb01 : wa01;   // jj 4,5
        pf[ks].w[3] = hi ? wb23 : wa23;   // jj 6,7
      }

      // ---- PV: O[q][c] += P[q][j] V[j][c]
#pragma unroll
      for (int nt = 0; nt < 16; ++nt) {
        short8 b0 = *(short8*)&Vt[swV(nt * 16 + r, quad)];
        short8 b1 = *(short8*)&Vt[swV(nt * 16 + r, 4 + quad)];
        Oa[nt] = __builtin_amdgcn_mfma_f32_16x16x32_bf16(pf[0].v, b0, Oa[nt], 0, 0, 0);
        Oa[nt] = __builtin_amdgcn_mfma_f32_16x16x32_bf16(pf[1].v, b1, Oa[nt], 0, 0, 0);
      }
    } // kt

    // ---- finalize: per-row 1/l (or colsum fallback), LN, partial time-sum
    float mr[4], li[4];
#pragma unroll
    for (int reg = 0; reg < 4; ++reg) {
      mr[reg] = __shfl(m, quad * 4 + reg, 64);
      float lr = __shfl(l, quad * 4 + reg, 64);
      li[reg] = 1.f / lr;
    }
    float cs_[16], g_[16], be_[16];
#pragma unroll
    for (int nt = 0; nt < 16; ++nt) {
      int c = nt * 16 + r;
      cs_[nt] = colsum[b * C_ + c] * (1.0f / T_);
      g_[nt]  = gamma[c];
      be_[nt] = beta[c];
    }
#pragma unroll
    for (int nt = 0; nt < 16; ++nt) {
#pragma unroll
      for (int reg = 0; reg < 4; ++reg) {
        Oa[nt][reg] = (mr[reg] < -1.0e9f) ? cs_[nt] : Oa[nt][reg] * li[reg];
      }
    }
    float ts[16];
#pragma unroll
    for (int nt = 0; nt < 16; ++nt) ts[nt] = 0.f;
#pragma unroll
    for (int reg = 0; reg < 4; ++reg) {
      float s = 0.f;
#pragma unroll
      for (int nt = 0; nt < 16; ++nt) s += Oa[nt][reg];
      s += __shfl_xor(s, 1, 64); s += __shfl_xor(s, 2, 64);
      s += __shfl_xor(s, 4, 64); s += __shfl_xor(s, 8, 64);
      float mu = s * (1.0f / C_);
      float sq = 0.f;
#pragma unroll
      for (int nt = 0; nt < 16; ++nt) { float d = Oa[nt][reg] - mu; sq += d * d; }
      sq += __shfl_xor(sq, 1, 64); sq += __shfl_xor(sq, 2, 64);
      sq += __shfl_xor(sq, 4, 64); sq += __shfl_xor(sq, 8, 64);
      float rstd = rsqrtf(sq * (1.0f / C_) + LN_EPS);
#pragma unroll
      for (int nt = 0; nt < 16; ++nt)
        ts[nt] += g_[nt] * (Oa[nt][reg] - mu) * rstd + be_[nt];
    }
#pragma unroll
    for (int nt = 0; nt < 16; ++nt) {
      ts[nt] += __shfl_xor(ts[nt], 16, 64);
      ts[nt] += __shfl_xor(ts[nt], 32, 64);
    }
    if (quad == 0) {
#pragma unroll
      for (int nt = 0; nt < 16; ++nt)
        atomicAdd(&accum[b * C_ + nt * 16 + r], ts[nt]);
    }
  } // half
}

__global__ void finalize_kernel(const float* __restrict__ accum,
                                float* __restrict__ out) {
  int idx = blockIdx.x * 256 + threadIdx.x;   // B*C = 16384
  out[idx] = accum[idx] * (1.0f / T_);
}

extern "C" void kernel_launch(void* const* d_in, const int* in_sizes, int n_in,
                              void* d_out, int out_size, void* d_ws, size_t ws_size,
                              hipStream_t stream) {
  const float* x     = (const float*)d_in[0];
  const void*  km    = d_in[1];
  const float* gamma = (const float*)d_in[2];
  const float* beta  = (const float*)d_in[3];
  float* out = (float*)d_out;

  float* accum  = (float*)d_ws;                       // 16384 f
  float* colsum = accum + B_ * C_;                    // 16384 f
  int*   flag   = (int*)((char*)d_ws + 131072);
  unsigned char* mask8 = (unsigned char*)d_ws + 131136;

  hipMemsetAsync(d_ws, 0, 131136, stream);

  detect_kernel<<<64, 256, 0, stream>>>((const unsigned int*)km, flag);
  normalize_kernel<<<B_ * T_ / 256, 256, 0, stream>>>((const unsigned int*)km, flag, mask8);
  colsum_kernel<<<dim3(B_, 8), 256, 0, stream>>>(x, colsum);
  flash_mfma<<<B_ * 8, 256, 0, stream>>>(x, mask8, gamma, beta, colsum, accum);
  finalize_kernel<<<B_ * C_ / 256, 256, 0, stream>>>(accum, out);
}

// Round 3
// 227.788 us; speedup vs baseline: 7.9570x; 1.2343x over previous
//
#include <hip/hip_runtime.h>

#define B_   64
#define T_   1024
#define C_   256
#define NEGF (-4294967295.0f)   // float(-2**32+1) == -2^32, matches reference fp32 cast
#define LN_EPS 1e-9f

typedef short  short8 __attribute__((ext_vector_type(8)));
typedef float  f32x4  __attribute__((ext_vector_type(4)));

union S8 { short8 v; unsigned int w[4]; };

// float -> bf16 (RNE), packed pair
__device__ __forceinline__ unsigned int pk2(float x, float y) {
  unsigned a = __float_as_uint(x); a = (a + 0x7fffu + ((a >> 16) & 1u)) >> 16;
  unsigned b = __float_as_uint(y); b = (b + 0x7fffu + ((b >> 16) & 1u)) >> 16;
  return a | (b << 16);
}

__device__ __forceinline__ float fc(const float4& v, int e) {
  return e == 0 ? v.x : e == 1 ? v.y : e == 2 ? v.z : v.w;
}

// async global->LDS, 16 B per lane, lands at ldsbase + lane*16
__device__ __forceinline__ void async16(const void* g, void* l) {
  __builtin_amdgcn_global_load_lds(
      (const __attribute__((address_space(1))) void*)g,
      (__attribute__((address_space(3))) void*)l,
      16, 0, 0);
}

// ---------------- shared small kernels ----------------

__global__ void detect_kernel(const unsigned int* __restrict__ mw,
                              int* __restrict__ flag) {
  int idx = blockIdx.x * 256 + threadIdx.x;   // 16384 words, safe for u8 or i32 buffer
  if (mw[idx] > 1u) atomicOr(flag, 1);
}

__global__ void finalize_kernel(const float* __restrict__ accum,
                                float* __restrict__ out) {
  int idx = blockIdx.x * 256 + threadIdx.x;   // B*C = 16384
  out[idx] = accum[idx] * (1.0f / T_);
}

// ---------------- fast path: pre-pass ----------------

// sb[b*T+j] = mask ? (1/16, 0) : (0, NEGF)   -> score = s*scale + bias
__global__ void build_sb(const unsigned int* __restrict__ mw,
                         const int* __restrict__ flag,
                         float2* __restrict__ sb) {
  int idx = blockIdx.x * 256 + threadIdx.x;   // B*T = 65536
  int f = *flag;
  unsigned int w = mw[f ? (idx >> 2) : idx];
  unsigned int v = f ? ((w >> ((idx & 3) * 8)) & 0xffu) : w;
  sb[idx] = v ? make_float2(0.0625f, 0.f) : make_float2(0.f, NEGF);
}

// One block per (b, 32-row tile): build bf16 K-image (row major, swizzled) and
// bf16 V^T-image (transposed, swizzled) + fp32 colsum, reading x exactly once.
__global__ __launch_bounds__(256) void convert_kv(const float* __restrict__ x,
                                                  short* __restrict__ xk,
                                                  short* __restrict__ xv,
                                                  float* __restrict__ colsum) {
  __shared__ float Xt[32 * 256];   // 32 KB fp32 tile [j][c]
  const int blk = blockIdx.x, b = blk >> 5, tt = blk & 31;
  const int tid = threadIdx.x;
  const float* xt = x + (size_t)(b * 1024 + tt * 32) * 256;

  // phase 1: coalesced row reads -> LDS fp32 + swizzled bf16 K-image
#pragma unroll
  for (int u = 0; u < 4; ++u) {
    int id = u * 256 + tid;            // 1024 items: 32 rows x 32 chunks
    int row = id >> 5, ck = id & 31;
    const float* src = xt + row * 256 + ck * 8;
    float4 a  = *(const float4*)src;
    float4 c4 = *(const float4*)(src + 4);
    *(float4*)&Xt[row * 256 + ck * 8]     = a;
    *(float4*)&Xt[row * 256 + ck * 8 + 4] = c4;
    S8 s; s.w[0] = pk2(a.x, a.y);  s.w[1] = pk2(a.z, a.w);
          s.w[2] = pk2(c4.x, c4.y); s.w[3] = pk2(c4.z, c4.w);
    *(short8*)(xk + (size_t)(b * 1024 + tt * 32 + row) * 256 + ((ck ^ row) << 3)) = s.v;
  }
  __syncthreads();

  // phase 2: transpose from LDS -> swizzled V^T image + colsum partials
  const int ck = tid >> 6, clo = tid & 63;
  short* vout = xv + (size_t)(b * 32 + tt) * 8192;
#pragma unroll
  for (int g = 0; g < 4; ++g) {
    int c = g * 64 + clo;
    float vs[8]; float s = 0.f;
#pragma unroll
    for (int e = 0; e < 8; ++e) { vs[e] = Xt[(ck * 8 + e) * 256 + c]; s += vs[e]; }
    S8 o;
    o.w[0] = pk2(vs[0], vs[1]); o.w[1] = pk2(vs[2], vs[3]);
    o.w[2] = pk2(vs[4], vs[5]); o.w[3] = pk2(vs[6], vs[7]);
    *(short8*)(vout + c * 32 + (((ck ^ ((c >> 1) & 3)) & 3) << 3)) = o.v;
    atomicAdd(&colsum[b * 256 + c], s);
  }
}

// ---------------- fast path: flash kernel ----------------
// Block = 4 waves, batch b, qt pair (p, 15-p). 32-key tiles, double-buffered
// async staging, one barrier per tile. Wave w owns 16 q rows.
__global__ __launch_bounds__(256, 2) void flash2(
    const short* __restrict__ xk,
    const short* __restrict__ xv,
    const float2* __restrict__ sb,
    const float* __restrict__ gamma,
    const float* __restrict__ beta,
    const float* __restrict__ colsum,
    float* __restrict__ accum)
{
  __shared__ __align__(16) short KsD[2][32 * 256];   // 2 x 16 KB
  __shared__ __align__(16) short VtD[2][256 * 32];   // 2 x 16 KB

  const int tid  = threadIdx.x;
  const int b    = blockIdx.x >> 3;
  const int pp   = blockIdx.x & 7;
  const int w    = tid >> 6;
  const int lane = tid & 63;
  const int quad = lane >> 4;
  const int r    = lane & 15;

  for (int half = 0; half < 2; ++half) {
    const int qt   = half ? (15 - pp) : pp;
    const int nk   = 2 * (qt + 1);
    const int qrow = qt * 64 + w * 16 + r;
    const int wmin = qt * 64 + w * 16;

    // Q fragments from the pre-swizzled bf16 K-image (no conversion)
    short8 qf[8];
#pragma unroll
    for (int ks = 0; ks < 8; ++ks) {
      qf[ks] = *(const short8*)(xk + (size_t)(b * 1024 + qrow) * 256 +
                                (((ks * 4 + quad) ^ (qrow & 31)) << 3));
    }

    f32x4 Oa[16];
#pragma unroll
    for (int nt = 0; nt < 16; ++nt) Oa[nt] = (f32x4){0.f, 0.f, 0.f, 0.f};
    float m = NEGF, l = 0.f;

    // prefetch tile 0 into buf 0
    {
      const short* gk = xk + (size_t)(b * 1024) * 256;
      const short* gv = xv + (size_t)(b * 32) * 8192;
#pragma unroll
      for (int u = 0; u < 4; ++u) {
        int is = w * 4 + u;
        async16(gk + is * 512 + lane * 8, &KsD[0][is * 512]);
        async16(gv + is * 512 + lane * 8, &VtD[0][is * 512]);
      }
    }
    __syncthreads();

    for (int kt = 0; kt < nk; ++kt) {
      const int i = kt & 1;
      if (kt + 1 < nk) {   // prefetch next tile into other buffer (async)
        const short* gk = xk + (size_t)(b * 1024 + (kt + 1) * 32) * 256;
        const short* gv = xv + (size_t)(b * 32 + (kt + 1)) * 8192;
#pragma unroll
        for (int u = 0; u < 4; ++u) {
          int is = w * 4 + u;
          async16(gk + is * 512 + lane * 8, &KsD[1 - i][is * 512]);
          async16(gv + is * 512 + lane * 8, &VtD[1 - i][is * 512]);
        }
      }

      if (kt * 32 <= wmin + 15) {     // wave-uniform: tile intersects causal range
        const int ktb = kt * 32;
        // ---- scores S^T = K·Q^T
        float sc[8];
#pragma unroll
        for (int mt = 0; mt < 2; ++mt) {
          f32x4 acc = (f32x4){0.f, 0.f, 0.f, 0.f};
          const int row = mt * 16 + r;
#pragma unroll
          for (int ks = 0; ks < 8; ++ks) {
            short8 af = *(short8*)&KsD[i][row * 256 + (((ks * 4 + quad) ^ row) << 3)];
            acc = __builtin_amdgcn_mfma_f32_16x16x32_bf16(af, qf[ks], acc, 0, 0, 0);
          }
          const int j0 = ktb + mt * 16 + quad * 4;
          float4 sA = *(const float4*)(sb + (size_t)b * 1024 + j0);     // s0,b0,s1,b1
          float4 sB = *(const float4*)(sb + (size_t)b * 1024 + j0 + 2); // s2,b2,s3,b3
          sc[mt * 4 + 0] = acc[0] * sA.x + sA.y;
          sc[mt * 4 + 1] = acc[1] * sA.z + sA.w;
          sc[mt * 4 + 2] = acc[2] * sB.x + sB.y;
          sc[mt * 4 + 3] = acc[3] * sB.z + sB.w;
        }
        if (ktb + 31 > wmin) {        // diagonal tiles: causal mask
#pragma unroll
          for (int k2 = 0; k2 < 8; ++k2) {
            int j = ktb + (k2 >> 2) * 16 + quad * 4 + (k2 & 3);
            if (j > qrow) sc[k2] = NEGF;
          }
        }

        // ---- online softmax (stats per q at lane&15, replicated via xor16/32)
        float mx = sc[0];
#pragma unroll
        for (int k2 = 1; k2 < 8; ++k2) mx = fmaxf(mx, sc[k2]);
        mx = fmaxf(mx, __shfl_xor(mx, 16, 64));
        mx = fmaxf(mx, __shfl_xor(mx, 32, 64));
        float mnew  = fmaxf(m, mx);
        float alpha = __expf(m - mnew);   // NEGF-NEGF=0 -> 1; NEGF-real -> 0
        float p[8], ps = 0.f;
#pragma unroll
        for (int k2 = 0; k2 < 8; ++k2) { p[k2] = __expf(sc[k2] - mnew); ps += p[k2]; }
        ps += __shfl_xor(ps, 16, 64);
        ps += __shfl_xor(ps, 32, 64);
        l = l * alpha + ps;
        m = mnew;

        if (__ballot(alpha < 1.0f)) {   // skip rescale when no max update anywhere
          float ar[4];
#pragma unroll
          for (int reg = 0; reg < 4; ++reg) ar[reg] = __shfl(alpha, quad * 4 + reg, 64);
#pragma unroll
          for (int nt = 0; nt < 16; ++nt) {
            Oa[nt][0] *= ar[0]; Oa[nt][1] *= ar[1];
            Oa[nt][2] *= ar[2]; Oa[nt][3] *= ar[3];
          }
        }

        // ---- P (C-layout) -> single PV A-frag via 8 shuffles
        unsigned q0 = pk2(p[0], p[1]), q1 = pk2(p[2], p[3]);
        unsigned q2 = pk2(p[4], p[5]), q3 = pk2(p[6], p[7]);
        int s0l = ((quad & 1) << 5) + r, s1l = s0l + 16;
        unsigned u0 = __shfl((int)q0, s0l, 64), u1 = __shfl((int)q1, s0l, 64);
        unsigned u2 = __shfl((int)q2, s0l, 64), u3 = __shfl((int)q3, s0l, 64);
        unsigned v0 = __shfl((int)q0, s1l, 64), v1 = __shfl((int)q1, s1l, 64);
        unsigned v2 = __shfl((int)q2, s1l, 64), v3 = __shfl((int)q3, s1l, 64);
        bool hi = quad >= 2;
        S8 pf;
        pf.w[0] = hi ? u2 : u0; pf.w[1] = hi ? u3 : u1;
        pf.w[2] = hi ? v2 : v0; pf.w[3] = hi ? v3 : v1;

        // ---- PV: O[q][c] += P[q][j] V[j][c]   (k=32: one MFMA per 16-col tile)
#pragma unroll
        for (int nt = 0; nt < 16; ++nt) {
          int c = nt * 16 + r;
          short8 bf = *(short8*)&VtD[i][c * 32 + (((quad ^ ((c >> 1) & 3)) & 3) << 3)];
          Oa[nt] = __builtin_amdgcn_mfma_f32_16x16x32_bf16(pf.v, bf, Oa[nt], 0, 0, 0);
        }
      }
      __syncthreads();   // drains prefetched tile kt+1 (issued a full tile ago)
    } // kt

    // ---- finalize: 1/l (or colsum fallback), LN, partial time-sum
    float mr[4], li[4];
#pragma unroll
    for (int reg = 0; reg < 4; ++reg) {
      mr[reg] = __shfl(m, quad * 4 + reg, 64);
      float lr = __shfl(l, quad * 4 + reg, 64);
      li[reg] = 1.f / lr;
    }
    float cs_[16], g_[16], be_[16];
#pragma unroll
    for (int nt = 0; nt < 16; ++nt) {
      int c = nt * 16 + r;
      cs_[nt] = colsum[b * C_ + c] * (1.0f / T_);
      g_[nt]  = gamma[c];
      be_[nt] = beta[c];
    }
#pragma unroll
    for (int nt = 0; nt < 16; ++nt) {
#pragma unroll
      for (int reg = 0; reg < 4; ++reg) {
        Oa[nt][reg] = (mr[reg] < -1.0e9f) ? cs_[nt] : Oa[nt][reg] * li[reg];
      }
    }
    float ts[16];
#pragma unroll
    for (int nt = 0; nt < 16; ++nt) ts[nt] = 0.f;
#pragma unroll
    for (int reg = 0; reg < 4; ++reg) {
      float s = 0.f;
#pragma unroll
      for (int nt = 0; nt < 16; ++nt) s += Oa[nt][reg];
      s += __shfl_xor(s, 1, 64); s += __shfl_xor(s, 2, 64);
      s += __shfl_xor(s, 4, 64); s += __shfl_xor(s, 8, 64);
      float mu = s * (1.0f / C_);
      float sq = 0.f;
#pragma unroll
      for (int nt = 0; nt < 16; ++nt) { float d = Oa[nt][reg] - mu; sq += d * d; }
      sq += __shfl_xor(sq, 1, 64); sq += __shfl_xor(sq, 2, 64);
      sq += __shfl_xor(sq, 4, 64); sq += __shfl_xor(sq, 8, 64);
      float rstd = rsqrtf(sq * (1.0f / C_) + LN_EPS);
#pragma unroll
      for (int nt = 0; nt < 16; ++nt)
        ts[nt] += g_[nt] * (Oa[nt][reg] - mu) * rstd + be_[nt];
    }
#pragma unroll
    for (int nt = 0; nt < 16; ++nt) {
      ts[nt] += __shfl_xor(ts[nt], 16, 64);
      ts[nt] += __shfl_xor(ts[nt], 32, 64);
    }
    if (quad == 0) {
#pragma unroll
      for (int nt = 0; nt < 16; ++nt)
        atomicAdd(&accum[b * C_ + nt * 16 + r], ts[nt]);
    }
  } // half
}

// ---------------- fallback path (round-2, verbatim) ----------------

__device__ __forceinline__ int sw_oldK(int row, int chunk) {
  return row * 256 + ((chunk ^ (row & 31)) << 3);
}
__device__ __forceinline__ int sw_oldV(int c, int chunk) {
  return c * 64 + (((chunk ^ (c >> 2) ^ (c << 1)) & 7) << 3);
}

__global__ void normalize_kernel(const unsigned int* __restrict__ mw,
                                 const int* __restrict__ flag,
                                 unsigned char* __restrict__ mask8) {
  int idx = blockIdx.x * 256 + threadIdx.x;
  int f = *flag;
  unsigned int w = mw[f ? (idx >> 2) : idx];
  unsigned int v = f ? ((w >> ((idx & 3) * 8)) & 0xffu) : w;
  mask8[idx] = (unsigned char)(v != 0u);
}

__global__ void colsum_kernel(const float* __restrict__ x,
                              float* __restrict__ colsum) {
  int b = blockIdx.x, chunk = blockIdx.y, c = threadIdx.x;
  const float* xp = x + ((size_t)b * T_ + (size_t)chunk * 128) * C_ + c;
  float s = 0.f;
  for (int t = 0; t < 128; ++t) s += xp[(size_t)t * C_];
  atomicAdd(&colsum[b * C_ + c], s);
}

__global__ __launch_bounds__(256, 2) void flash_mfma(
    const float* __restrict__ x,
    const unsigned char* __restrict__ mask,
    const float* __restrict__ gamma,
    const float* __restrict__ beta,
    const float* __restrict__ colsum,
    float* __restrict__ accum)
{
  __shared__ __align__(16) short Ks[64 * 256];
  __shared__ __align__(16) short Vt[256 * 64];

  const int tid  = threadIdx.x;
  const int b    = blockIdx.x >> 3;
  const int pp   = blockIdx.x & 7;
  const int w    = tid >> 6;
  const int lane = tid & 63;
  const int quad = lane >> 4;
  const int r    = lane & 15;

  const float* xb = x + (size_t)b * (T_ * C_);
  const unsigned char* mb = mask + b * T_;
  const int cg = tid & 63, kg0 = tid >> 6;

  for (int half = 0; half < 2; ++half) {
    const int qt   = half ? (15 - pp) : pp;
    const int qrow = qt * 64 + w * 16 + r;

    short8 qf[8];
#pragma unroll
    for (int ks = 0; ks < 8; ++ks) {
      const float* src = xb + (size_t)qrow * C_ + ks * 32 + quad * 8;
      float4 a  = *(const float4*)src;
      float4 c4 = *(const float4*)(src + 4);
      S8 s; s.w[0] = pk2(a.x, a.y);  s.w[1] = pk2(a.z, a.w);
            s.w[2] = pk2(c4.x, c4.y); s.w[3] = pk2(c4.z, c4.w);
      qf[ks] = s.v;
    }

    f32x4 Oa[16];
#pragma unroll
    for (int nt = 0; nt < 16; ++nt) Oa[nt] = (f32x4){0.f, 0.f, 0.f, 0.f};
    float m = NEGF, l = 0.f;

    for (int kt = 0; kt <= qt; ++kt) {
      __syncthreads();
#pragma unroll
      for (int v = 0; v < 8; ++v) {
        int id = v * 256 + tid;
        int row = id >> 5, ck = id & 31;
        const float* src = xb + (size_t)(kt * 64 + row) * C_ + (ck << 3);
        float4 a  = *(const float4*)src;
        float4 c4 = *(const float4*)(src + 4);
        S8 s; s.w[0] = pk2(a.x, a.y);  s.w[1] = pk2(a.z, a.w);
              s.w[2] = pk2(c4.x, c4.y); s.w[3] = pk2(c4.z, c4.w);
        *(short8*)&Ks[sw_oldK(row, ck)] = s.v;
      }
#pragma unroll
      for (int u = 0; u < 2; ++u) {
        int kg = kg0 + u * 4;
        const float* src = xb + (size_t)(kt * 64 + kg * 8) * C_ + (cg << 2);
        float4 rv[8];
#pragma unroll
        for (int rr = 0; rr < 8; ++rr) rv[rr] = *(const float4*)(src + rr * C_);
#pragma unroll
        for (int e = 0; e < 4; ++e) {
          S8 s;
          s.w[0] = pk2(fc(rv[0], e), fc(rv[1], e));
          s.w[1] = pk2(fc(rv[2], e), fc(rv[3], e));
          s.w[2] = pk2(fc(rv[4], e), fc(rv[5], e));
          s.w[3] = pk2(fc(rv[6], e), fc(rv[7], e));
          *(short8*)&Vt[sw_oldV(cg * 4 + e, kg)] = s.v;
        }
      }
      __syncthreads();

      float sc[16];
#pragma unroll
      for (int mt = 0; mt < 4; ++mt) {
        f32x4 acc = (f32x4){0.f, 0.f, 0.f, 0.f};
#pragma unroll
        for (int ks = 0; ks < 8; ++ks) {
          short8 af = *(short8*)&Ks[sw_oldK(mt * 16 + r, ks * 4 + quad)];
          acc = __builtin_amdgcn_mfma_f32_16x16x32_bf16(af, qf[ks], acc, 0, 0, 0);
        }
        const int jb = kt * 64 + mt * 16 + quad * 4;
#pragma unroll
        for (int reg = 0; reg < 4; ++reg) {
          int j = jb + reg;
          sc[mt * 4 + reg] = (j <= qrow && mb[j]) ? acc[reg] * 0.0625f : NEGF;
        }
      }

      float mx = sc[0];
#pragma unroll
      for (int i = 1; i < 16; ++i) mx = fmaxf(mx, sc[i]);
      mx = fmaxf(mx, __shfl_xor(mx, 16, 64));
      mx = fmaxf(mx, __shfl_xor(mx, 32, 64));
      float mnew  = fmaxf(m, mx);
      float alpha = __expf(m - mnew);
      float p[16], ps = 0.f;
#pragma unroll
      for (int i = 0; i < 16; ++i) { p[i] = __expf(sc[i] - mnew); ps += p[i]; }
      ps += __shfl_xor(ps, 16, 64);
      ps += __shfl_xor(ps, 32, 64);
      l = l * alpha + ps;
      m = mnew;

      float ar[4];
#pragma unroll
      for (int reg = 0; reg < 4; ++reg) ar[reg] = __shfl(alpha, quad * 4 + reg, 64);
#pragma unroll
      for (int nt = 0; nt < 16; ++nt) {
        Oa[nt][0] *= ar[0]; Oa[nt][1] *= ar[1];
        Oa[nt][2] *= ar[2]; Oa[nt][3] *= ar[3];
      }

      S8 pf[2];
#pragma unroll
      for (int ks = 0; ks < 2; ++ks) {
        unsigned a01 = pk2(p[ks * 8 + 0], p[ks * 8 + 1]);
        unsigned a23 = pk2(p[ks * 8 + 2], p[ks * 8 + 3]);
        unsigned b01 = pk2(p[ks * 8 + 4], p[ks * 8 + 5]);
        unsigned b23 = pk2(p[ks * 8 + 6], p[ks * 8 + 7]);
        int s0 = ((quad & 1) << 5) + r;
        int s1 = s0 + 16;
        unsigned va01 = __shfl((int)a01, s0, 64), vb01 = __shfl((int)b01, s0, 64);
        unsigned va23 = __shfl((int)a23, s0, 64), vb23 = __shfl((int)b23, s0, 64);
        unsigned wa01 = __shfl((int)a01, s1, 64), wb01 = __shfl((int)b01, s1, 64);
        unsigned wa23 = __shfl((int)a23, s1, 64), wb23 = __shfl((int)b23, s1, 64);
        bool hi = (quad & 2) != 0;
        pf[ks].w[0] = hi ? vb01 : va01;
        pf[ks].w[1] = hi ? vb23 : va23;
        pf[ks].w[2] = hi ? wb01 : wa01;
        pf[ks].w[3] = hi ? wb23 : wa23;
      }

#pragma unroll
      for (int nt = 0; nt < 16; ++nt) {
        short8 b0 = *(short8*)&Vt[sw_oldV(nt * 16 + r, quad)];
        short8 b1 = *(short8*)&Vt[sw_oldV(nt * 16 + r, 4 + quad)];
        Oa[nt] = __builtin_amdgcn_mfma_f32_16x16x32_bf16(pf[0].v, b0, Oa[nt], 0, 0, 0);
        Oa[nt] = __builtin_amdgcn_mfma_f32_16x16x32_bf16(pf[1].v, b1, Oa[nt], 0, 0, 0);
      }
    } // kt

    float mr[4], li[4];
#pragma unroll
    for (int reg = 0; reg < 4; ++reg) {
      mr[reg] = __shfl(m, quad * 4 + reg, 64);
      float lr = __shfl(l, quad * 4 + reg, 64);
      li[reg] = 1.f / lr;
    }
    float cs_[16], g_[16], be_[16];
#pragma unroll
    for (int nt = 0; nt < 16; ++nt) {
      int c = nt * 16 + r;
      cs_[nt] = colsum[b * C_ + c] * (1.0f / T_);
      g_[nt]  = gamma[c];
      be_[nt] = beta[c];
    }
#pragma unroll
    for (int nt = 0; nt < 16; ++nt) {
#pragma unroll
      for (int reg = 0; reg < 4; ++reg) {
        Oa[nt][reg] = (mr[reg] < -1.0e9f) ? cs_[nt] : Oa[nt][reg] * li[reg];
      }
    }
    float ts[16];
#pragma unroll
    for (int nt = 0; nt < 16; ++nt) ts[nt] = 0.f;
#pragma unroll
    for (int reg = 0; reg < 4; ++reg) {
      float s = 0.f;
#pragma unroll
      for (int nt = 0; nt < 16; ++nt) s += Oa[nt][reg];
      s += __shfl_xor(s, 1, 64); s += __shfl_xor(s, 2, 64);
      s += __shfl_xor(s, 4, 64); s += __shfl_xor(s, 8, 64);
      float mu = s * (1.0f / C_);
      float sq = 0.f;
#pragma unroll
      for (int nt = 0; nt < 16; ++nt) { float d = Oa[nt][reg] - mu; sq += d * d; }
      sq += __shfl_xor(sq, 1, 64); sq += __shfl_xor(sq, 2, 64);
      sq += __shfl_xor(sq, 4, 64); sq += __shfl_xor(sq, 8, 64);
      float rstd = rsqrtf(sq * (1.0f / C_) + LN_EPS);
#pragma unroll
      for (int nt = 0; nt < 16; ++nt)
        ts[nt] += g_[nt] * (Oa[nt][reg] - mu) * rstd + be_[nt];
    }
#pragma unroll
    for (int nt = 0; nt < 16; ++nt) {
      ts[nt] += __shfl_xor(ts[nt], 16, 64);
      ts[nt] += __shfl_xor(ts[nt], 32, 64);
    }
    if (quad == 0) {
#pragma unroll
      for (int nt = 0; nt < 16; ++nt)
        atomicAdd(&accum[b * C_ + nt * 16 + r], ts[nt]);
    }
  } // half
}

// ---------------- launch ----------------

extern "C" void kernel_launch(void* const* d_in, const int* in_sizes, int n_in,
                              void* d_out, int out_size, void* d_ws, size_t ws_size,
                              hipStream_t stream) {
  const float* x     = (const float*)d_in[0];
  const void*  km    = d_in[1];
  const float* gamma = (const float*)d_in[2];
  const float* beta  = (const float*)d_in[3];
  float* out = (float*)d_out;

  // fast-path ws layout
  const size_t off_sb = 131200;                       // float2[B*T] = 512 KB
  const size_t off_xk = 655616;                       // 32 MB bf16 K-image
  const size_t off_xv = off_xk + 33554432;            // 32 MB bf16 V^T-image
  const size_t need   = off_xv + 33554432;            // ~64.6 MB

  float* accum  = (float*)d_ws;
  float* colsum = (float*)((char*)d_ws + 65536);
  int*   flag   = (int*)((char*)d_ws + 131072);

  hipMemsetAsync(d_ws, 0, 131200, stream);
  detect_kernel<<<64, 256, 0, stream>>>((const unsigned int*)km, flag);

  if (ws_size >= need) {
    float2* sb = (float2*)((char*)d_ws + off_sb);
    short*  xk = (short*)((char*)d_ws + off_xk);
    short*  xv = (short*)((char*)d_ws + off_xv);
    build_sb<<<B_ * T_ / 256, 256, 0, stream>>>((const unsigned int*)km, flag, sb);
    convert_kv<<<B_ * 32, 256, 0, stream>>>(x, xk, xv, colsum);
    flash2<<<B_ * 8, 256, 0, stream>>>(xk, xv, sb, gamma, beta, colsum, accum);
  } else {
    unsigned char* mask8 = (unsigned char*)d_ws + 131136;
    normalize_kernel<<<B_ * T_ / 256, 256, 0, stream>>>((const unsigned int*)km, flag, mask8);
    colsum_kernel<<<dim3(B_, 8), 256, 0, stream>>>(x, colsum);
    flash_mfma<<<B_ * 8, 256, 0, stream>>>(x, mask8, gamma, beta, colsum, accum);
  }
  finalize_kernel<<<B_ * C_ / 256, 256, 0, stream>>>(accum, out);
}